// Round 6
// baseline (128.875 us; speedup 1.0000x reference)
//
#include <hip/hip_runtime.h>

#define B_ 2048
#define S_ 256
#define V_ 30522
#define D_ 768
#define C_ 100
#define NPAD 112  // C_ padded to 7x16 for MFMA col tiles

// ---- bf16 helpers (RNE convert; inputs are finite, no NaN handling) -------
__device__ __forceinline__ unsigned short f2bf(float x) {
  unsigned u = __builtin_bit_cast(unsigned, x);
  u = (u + 0x7fffu + ((u >> 16) & 1u)) >> 16;
  return (unsigned short)u;
}

typedef __attribute__((ext_vector_type(8))) short bf16x8;
typedef __attribute__((ext_vector_type(4))) float f32x4;

// ---------------------------------------------------------------------------
// Compact valid token ids per sample: cids[b][0..cnt), cnts[b].
// One wave per sample; 512 blocks x 256 threads.
// ---------------------------------------------------------------------------
__global__ __launch_bounds__(256) void compact_ids(
    const int* __restrict__ ids, const int* __restrict__ mask,
    int* __restrict__ cids, int* __restrict__ cnts) {
  const int wv = threadIdx.x >> 6, lane = threadIdx.x & 63;
  const int b = blockIdx.x * 4 + wv;
  const int base = b * S_;
  int total = 0;
#pragma unroll
  for (int r = 0; r < S_ / 64; ++r) {
    const int s = r * 64 + lane;
    const int m = mask[base + s];
    const unsigned long long bal = __ballot(m != 0);
    const int pre = __popcll(bal & ((1ull << lane) - 1ull));
    if (m) cids[base + total + pre] = ids[base + s];
    total += __popcll(bal);
  }
  if (lane == 0) cnts[b] = total;
}

// ---------------------------------------------------------------------------
// Pool v3: XCD-pinned column-sliced gather from the **f32** table.
// 24 chunks of 32 f32 cols (128 B slice-row, line-aligned; slice 3.9 MB fits
// one XCD's 4 MB L2). Grid 3*512: pass p = b>>9, chunk = p*8 + (b&7) so each
// XCD (= bid%8) reads one L2-resident slice per pass. Block: 256 thr, wave wv
// pools 8 samples of its 32-sample group; lane = 8 token-slots x 8 col-groups.
// Per-wave LDS id stage; shfl_xor(8,16,32) reduce; bf16 bow output.
// ---------------------------------------------------------------------------
__global__ __launch_bounds__(256) void pool_sliced(
    const int* __restrict__ cids, const int* __restrict__ cnts,
    const float* __restrict__ table, unsigned short* __restrict__ bowb) {
  __shared__ int sids[4][S_];
  const int b = blockIdx.x;
  const int p = b >> 9;            // pass 0..2
  const int q = b & 511;
  const int chunk = p * 8 + (q & 7);
  const int grp = q >> 3;          // 0..63
  const int wv = threadIdx.x >> 6;
  const int lane = threadIdx.x & 63;
  const int sub = lane >> 3;       // token slot 0..7
  const int cg = lane & 7;         // col group (4 f32)
  const int coff = chunk * 32 + cg * 4;

  for (int i = 0; i < 8; ++i) {
    const int smp = grp * 32 + wv * 8 + i;
    const int cnt = cnts[smp];
    const int* cp = cids + (size_t)smp * S_;
    // stage ids to LDS (same-wave write->read, no barrier needed)
#pragma unroll
    for (int r = 0; r < S_ / 64; ++r) {
      const int idx = r * 64 + lane;
      sids[wv][idx] = (idx < cnt) ? cp[idx] : cp[0];
    }
    float a0 = 0.f, a1 = 0.f, a2 = 0.f, a3 = 0.f;
    for (int base = 0; base < cnt; base += 32) {
      float4 v[4];
#pragma unroll
      for (int j = 0; j < 4; ++j) {
        int t = base + j * 8 + sub;
        t = t < S_ ? t : S_ - 1;
        const int id = sids[wv][t];
        v[j] = *reinterpret_cast<const float4*>(table + (size_t)id * D_ + coff);
      }
#pragma unroll
      for (int j = 0; j < 4; ++j) {
        if (base + j * 8 + sub < cnt) {
          a0 += v[j].x; a1 += v[j].y; a2 += v[j].z; a3 += v[j].w;
        }
      }
    }
    // reduce over token slots (lane bits 3,4,5)
#pragma unroll
    for (int m = 8; m <= 32; m <<= 1) {
      a0 += __shfl_xor(a0, m);
      a1 += __shfl_xor(a1, m);
      a2 += __shfl_xor(a2, m);
      a3 += __shfl_xor(a3, m);
    }
    if (sub == 0) {
      const float inv = 1.0f / (float)cnt;
      ushort4 o;
      o.x = f2bf(a0 * inv); o.y = f2bf(a1 * inv);
      o.z = f2bf(a2 * inv); o.w = f2bf(a3 * inv);
      *reinterpret_cast<ushort4*>(bowb + (size_t)smp * D_ + coff) = o;
    }
  }
}

// ---------------------------------------------------------------------------
// Transpose + convert W1 [768][768] f32 -> W1T [n][k] bf16
// ---------------------------------------------------------------------------
__global__ __launch_bounds__(256) void conv_w1t(
    const float* __restrict__ w1, unsigned short* __restrict__ w1t) {
  __shared__ float tile[32][33];
  const int k0 = blockIdx.x * 32, n0 = blockIdx.y * 32;
  const int tx = threadIdx.x & 31, ty = threadIdx.x >> 5;  // ty 0..7
#pragma unroll
  for (int i = 0; i < 4; ++i)
    tile[ty + i * 8][tx] = w1[(size_t)(k0 + ty + i * 8) * D_ + n0 + tx];
  __syncthreads();
#pragma unroll
  for (int i = 0; i < 4; ++i) {
    const int n = ty + i * 8;
    w1t[(size_t)(n0 + n) * D_ + k0 + tx] = f2bf(tile[tx][n]);
  }
}

// ---------------------------------------------------------------------------
// Transpose + convert W2 [768][100] f32 -> W2T [112][768] bf16 (zero-padded)
// ---------------------------------------------------------------------------
__global__ __launch_bounds__(256) void conv_w2t(
    const float* __restrict__ w2, unsigned short* __restrict__ w2t) {
  __shared__ float tile[32][33];
  const int k0 = blockIdx.x * 32, n0 = blockIdx.y * 32;
  const int tx = threadIdx.x & 31, ty = threadIdx.x >> 5;
#pragma unroll
  for (int i = 0; i < 4; ++i) {
    const int k = k0 + ty + i * 8, n = n0 + tx;
    tile[ty + i * 8][tx] = (n < C_) ? w2[(size_t)k * C_ + n] : 0.f;
  }
  __syncthreads();
#pragma unroll
  for (int i = 0; i < 4; ++i) {
    const int n = n0 + ty + i * 8;
    if (n < NPAD)
      w2t[(size_t)n * D_ + k0 + tx] = f2bf(tile[tx][ty + i * 8]);
  }
}

// ---------------------------------------------------------------------------
// GEMM1 (MFMA bf16): Hb = relu(bow @ W1 + b1), stored as bf16.
// ---------------------------------------------------------------------------
#define G1_BM 32
#define G1_BN 64
#define G1_LDK 40  // 32 + 8 pad (ushorts) -> 80B row stride, 16B aligned

__global__ __launch_bounds__(256) void gemm1_mfma(
    const unsigned short* __restrict__ Ab, const unsigned short* __restrict__ Bt,
    const float* __restrict__ bias, unsigned short* __restrict__ Hb) {
  __shared__ unsigned short As[G1_BM][G1_LDK];
  __shared__ unsigned short Bs[G1_BN][G1_LDK];
  const int tid = threadIdx.x;
  const int bm = blockIdx.x * G1_BM;
  const int bn = blockIdx.y * G1_BN;
  const int w = tid >> 6;
  const int l = tid & 63;
  const int r = l & 15;
  const int g = l >> 4;

  f32x4 acc0 = {0.f, 0.f, 0.f, 0.f};
  f32x4 acc1 = {0.f, 0.f, 0.f, 0.f};

  const int srow = tid >> 2;        // 0..63
  const int sc8 = (tid & 3) * 8;    // 0,8,16,24 (bf16 elems)

  for (int k0 = 0; k0 < D_; k0 += 32) {
    __syncthreads();
    if (tid < 128) {
      const int ar = tid >> 2;      // 0..31
      *reinterpret_cast<int4*>(&As[ar][sc8]) =
          *reinterpret_cast<const int4*>(&Ab[(size_t)(bm + ar) * D_ + k0 + sc8]);
    }
    *reinterpret_cast<int4*>(&Bs[srow][sc8]) =
        *reinterpret_cast<const int4*>(&Bt[(size_t)(bn + srow) * D_ + k0 + sc8]);
    __syncthreads();
    const bf16x8 av0 = *reinterpret_cast<const bf16x8*>(&As[r][g * 8]);
    const bf16x8 av1 = *reinterpret_cast<const bf16x8*>(&As[16 + r][g * 8]);
    const bf16x8 bv = *reinterpret_cast<const bf16x8*>(&Bs[w * 16 + r][g * 8]);
    acc0 = __builtin_amdgcn_mfma_f32_16x16x32_bf16(av0, bv, acc0, 0, 0, 0);
    acc1 = __builtin_amdgcn_mfma_f32_16x16x32_bf16(av1, bv, acc1, 0, 0, 0);
  }

  const int col = bn + w * 16 + r;
  const float bb = bias[col];
#pragma unroll
  for (int q = 0; q < 4; ++q) {
    const int row0 = bm + g * 4 + q;
    float v0 = acc0[q] + bb;
    v0 = v0 > 0.f ? v0 : 0.f;
    Hb[(size_t)row0 * D_ + col] = f2bf(v0);
    float v1 = acc1[q] + bb;
    v1 = v1 > 0.f ? v1 : 0.f;
    Hb[(size_t)(row0 + 16) * D_ + col] = f2bf(v1);
  }
}

// ---------------------------------------------------------------------------
// GEMM2 (MFMA bf16): scores = Hb @ W2 + b2, written twice (tuple return).
// ---------------------------------------------------------------------------
__global__ __launch_bounds__(64) void gemm2_mfma(
    const unsigned short* __restrict__ Hb, const unsigned short* __restrict__ w2t,
    const float* __restrict__ b2, float* __restrict__ out) {
  const int bm = blockIdx.x * 16;
  const int bn = blockIdx.y * 16;
  const int l = threadIdx.x;
  const int r = l & 15;
  const int g = l >> 4;

  const unsigned short* ap = Hb + (size_t)(bm + r) * D_ + g * 8;
  const unsigned short* bp = w2t + (size_t)(bn + r) * D_ + g * 8;

  f32x4 acc = {0.f, 0.f, 0.f, 0.f};
#pragma unroll
  for (int k0 = 0; k0 < D_; k0 += 32) {
    const bf16x8 av = *reinterpret_cast<const bf16x8*>(ap + k0);
    const bf16x8 bv = *reinterpret_cast<const bf16x8*>(bp + k0);
    acc = __builtin_amdgcn_mfma_f32_16x16x32_bf16(av, bv, acc, 0, 0, 0);
  }

  const int col = bn + r;
  if (col < C_) {
    const float bb = b2[col];
#pragma unroll
    for (int q = 0; q < 4; ++q) {
      const int row = bm + g * 4 + q;
      const float v = acc[q] + bb;
      out[(size_t)row * C_ + col] = v;
      out[(size_t)row * C_ + col + (size_t)B_ * C_] = v;
    }
  }
}

// ---------------------------------------------------------------------------
extern "C" void kernel_launch(void* const* d_in, const int* in_sizes, int n_in,
                              void* d_out, int out_size, void* d_ws,
                              size_t ws_size, hipStream_t stream) {
  const int* ids = (const int*)d_in[0];
  const int* mask = (const int*)d_in[1];
  const float* table = (const float*)d_in[2];
  const float* W1 = (const float*)d_in[3];
  const float* b1 = (const float*)d_in[4];
  const float* W2 = (const float*)d_in[5];
  const float* b2 = (const float*)d_in[6];
  float* out = (float*)d_out;

  const size_t BOWB = (size_t)B_ * D_ * 2;          // 3.1 MB
  const size_t HBB  = (size_t)B_ * D_ * 2;          // 3.1 MB
  const size_t W1TB = (size_t)D_ * D_ * 2;          // 1.2 MB
  const size_t W2TB = (size_t)NPAD * D_ * 2;        // 172 KB
  const size_t CIDB = (size_t)B_ * S_ * 4;          // 2.1 MB

  char* p = (char*)d_ws;
  unsigned short* bowb = (unsigned short*)p;
  unsigned short* hb   = (unsigned short*)(p + BOWB);
  unsigned short* w1t  = (unsigned short*)(p + BOWB + HBB);
  unsigned short* w2t  = (unsigned short*)(p + BOWB + HBB + W1TB);
  int* cids            = (int*)(p + BOWB + HBB + W1TB + W2TB);
  int* cnts            = (int*)(p + BOWB + HBB + W1TB + W2TB + CIDB);

  compact_ids<<<B_ / 4, 256, 0, stream>>>(ids, mask, cids, cnts);
  conv_w1t<<<dim3(D_ / 32, D_ / 32), 256, 0, stream>>>(W1, w1t);
  conv_w2t<<<dim3(D_ / 32, 4), 256, 0, stream>>>(W2, w2t);
  pool_sliced<<<3 * 512, 256, 0, stream>>>(cids, cnts, table, bowb);
  gemm1_mfma<<<dim3(B_ / G1_BM, D_ / G1_BN), 256, 0, stream>>>(bowb, w1t, b1, hb);
  gemm2_mfma<<<dim3(B_ / 16, NPAD / 16), 64, 0, stream>>>(hb, w2t, b2, out);
}

// Round 7
// 103.974 us; speedup vs baseline: 1.2395x; 1.2395x over previous
//
#include <hip/hip_runtime.h>

#define B_ 2048
#define S_ 256
#define V_ 30522
#define D_ 768
#define C_ 100
#define NPAD 112  // C_ padded to 7x16 for MFMA col tiles

// ---- bf16 helpers (RNE convert; inputs are finite, no NaN handling) -------
__device__ __forceinline__ unsigned short f2bf(float x) {
  unsigned u = __builtin_bit_cast(unsigned, x);
  u = (u + 0x7fffu + ((u >> 16) & 1u)) >> 16;
  return (unsigned short)u;
}

typedef __attribute__((ext_vector_type(8))) short bf16x8;
typedef __attribute__((ext_vector_type(4))) float f32x4;

// ---------------------------------------------------------------------------
// Compact valid token ids per sample: cids[b][0..cnt), cnts[b].
// ---------------------------------------------------------------------------
__global__ __launch_bounds__(256) void compact_ids(
    const int* __restrict__ ids, const int* __restrict__ mask,
    int* __restrict__ cids, int* __restrict__ cnts) {
  const int wv = threadIdx.x >> 6, lane = threadIdx.x & 63;
  const int b = blockIdx.x * 4 + wv;
  const int base = b * S_;
  int total = 0;
#pragma unroll
  for (int r = 0; r < S_ / 64; ++r) {
    const int s = r * 64 + lane;
    const int m = mask[base + s];
    const unsigned long long bal = __ballot(m != 0);
    const int pre = __popcll(bal & ((1ull << lane) - 1ull));
    if (m) cids[base + total + pre] = ids[base + s];
    total += __popcll(bal);
  }
  if (lane == 0) cnts[b] = total;
}

// ---------------------------------------------------------------------------
// Pool v4: XCD-pinned column-sliced gather from the f32 table, ONE PASS PER
// LAUNCH (3 serialized launches). Per pass: 1024 blocks; chunk = pass*8 +
// (bid&7) so each XCD (= bid%8 round-robin dispatch) reads exactly one
// 30522x128B = 3.9 MB slice, L2-resident. Block: 256 thr; wave wv pools 4
// samples of its 16-sample group; lane = 8 token-slots x 8 col-groups.
// ---------------------------------------------------------------------------
__global__ __launch_bounds__(256) void pool_sliced(
    const int* __restrict__ cids, const int* __restrict__ cnts,
    const float* __restrict__ table, unsigned short* __restrict__ bowb,
    int pass) {
  __shared__ int sids[4][S_];
  const int bid = blockIdx.x;
  const int chunk = pass * 8 + (bid & 7);
  const int grp = bid >> 3;        // 0..127
  const int wv = threadIdx.x >> 6;
  const int lane = threadIdx.x & 63;
  const int sub = lane >> 3;       // token slot 0..7
  const int cg = lane & 7;         // col group (4 f32)
  const int coff = chunk * 32 + cg * 4;

  for (int i = 0; i < 4; ++i) {
    const int smp = grp * 16 + wv * 4 + i;
    const int cnt = cnts[smp];
    const int* cp = cids + (size_t)smp * S_;
    // stage ids to LDS (same-wave write->read, no barrier needed)
#pragma unroll
    for (int r = 0; r < S_ / 64; ++r) {
      const int idx = r * 64 + lane;
      sids[wv][idx] = (idx < cnt) ? cp[idx] : cp[0];
    }
    float a0 = 0.f, a1 = 0.f, a2 = 0.f, a3 = 0.f;
    for (int base = 0; base < cnt; base += 32) {
      float4 v[4];
#pragma unroll
      for (int j = 0; j < 4; ++j) {
        int t = base + j * 8 + sub;
        t = t < S_ ? t : S_ - 1;
        const int id = sids[wv][t];
        v[j] = *reinterpret_cast<const float4*>(table + (size_t)id * D_ + coff);
      }
#pragma unroll
      for (int j = 0; j < 4; ++j) {
        if (base + j * 8 + sub < cnt) {
          a0 += v[j].x; a1 += v[j].y; a2 += v[j].z; a3 += v[j].w;
        }
      }
    }
    // reduce over token slots (lane bits 3,4,5)
#pragma unroll
    for (int m = 8; m <= 32; m <<= 1) {
      a0 += __shfl_xor(a0, m);
      a1 += __shfl_xor(a1, m);
      a2 += __shfl_xor(a2, m);
      a3 += __shfl_xor(a3, m);
    }
    if (sub == 0) {
      const float inv = 1.0f / (float)cnt;
      ushort4 o;
      o.x = f2bf(a0 * inv); o.y = f2bf(a1 * inv);
      o.z = f2bf(a2 * inv); o.w = f2bf(a3 * inv);
      *reinterpret_cast<ushort4*>(bowb + (size_t)smp * D_ + coff) = o;
    }
  }
}

// ---------------------------------------------------------------------------
// Transpose + convert W1 [768][768] f32 -> W1T [n][k] bf16
// ---------------------------------------------------------------------------
__global__ __launch_bounds__(256) void conv_w1t(
    const float* __restrict__ w1, unsigned short* __restrict__ w1t) {
  __shared__ float tile[32][33];
  const int k0 = blockIdx.x * 32, n0 = blockIdx.y * 32;
  const int tx = threadIdx.x & 31, ty = threadIdx.x >> 5;  // ty 0..7
#pragma unroll
  for (int i = 0; i < 4; ++i)
    tile[ty + i * 8][tx] = w1[(size_t)(k0 + ty + i * 8) * D_ + n0 + tx];
  __syncthreads();
#pragma unroll
  for (int i = 0; i < 4; ++i) {
    const int n = ty + i * 8;
    w1t[(size_t)(n0 + n) * D_ + k0 + tx] = f2bf(tile[tx][n]);
  }
}

// ---------------------------------------------------------------------------
// Transpose + convert W2 [768][100] f32 -> W2T [112][768] bf16 (zero-padded)
// ---------------------------------------------------------------------------
__global__ __launch_bounds__(256) void conv_w2t(
    const float* __restrict__ w2, unsigned short* __restrict__ w2t) {
  __shared__ float tile[32][33];
  const int k0 = blockIdx.x * 32, n0 = blockIdx.y * 32;
  const int tx = threadIdx.x & 31, ty = threadIdx.x >> 5;
#pragma unroll
  for (int i = 0; i < 4; ++i) {
    const int k = k0 + ty + i * 8, n = n0 + tx;
    tile[ty + i * 8][tx] = (n < C_) ? w2[(size_t)k * C_ + n] : 0.f;
  }
  __syncthreads();
#pragma unroll
  for (int i = 0; i < 4; ++i) {
    const int n = n0 + ty + i * 8;
    if (n < NPAD)
      w2t[(size_t)n * D_ + k0 + tx] = f2bf(tile[tx][ty + i * 8]);
  }
}

// ---------------------------------------------------------------------------
// GEMM1 (MFMA bf16): Hb = relu(bow @ W1 + b1), stored as bf16.
// ---------------------------------------------------------------------------
#define G1_BM 32
#define G1_BN 64
#define G1_LDK 40  // 32 + 8 pad (ushorts) -> 80B row stride, 16B aligned

__global__ __launch_bounds__(256) void gemm1_mfma(
    const unsigned short* __restrict__ Ab, const unsigned short* __restrict__ Bt,
    const float* __restrict__ bias, unsigned short* __restrict__ Hb) {
  __shared__ unsigned short As[G1_BM][G1_LDK];
  __shared__ unsigned short Bs[G1_BN][G1_LDK];
  const int tid = threadIdx.x;
  const int bm = blockIdx.x * G1_BM;
  const int bn = blockIdx.y * G1_BN;
  const int w = tid >> 6;
  const int l = tid & 63;
  const int r = l & 15;
  const int g = l >> 4;

  f32x4 acc0 = {0.f, 0.f, 0.f, 0.f};
  f32x4 acc1 = {0.f, 0.f, 0.f, 0.f};

  const int srow = tid >> 2;        // 0..63
  const int sc8 = (tid & 3) * 8;    // 0,8,16,24 (bf16 elems)

  for (int k0 = 0; k0 < D_; k0 += 32) {
    __syncthreads();
    if (tid < 128) {
      const int ar = tid >> 2;      // 0..31
      *reinterpret_cast<int4*>(&As[ar][sc8]) =
          *reinterpret_cast<const int4*>(&Ab[(size_t)(bm + ar) * D_ + k0 + sc8]);
    }
    *reinterpret_cast<int4*>(&Bs[srow][sc8]) =
        *reinterpret_cast<const int4*>(&Bt[(size_t)(bn + srow) * D_ + k0 + sc8]);
    __syncthreads();
    const bf16x8 av0 = *reinterpret_cast<const bf16x8*>(&As[r][g * 8]);
    const bf16x8 av1 = *reinterpret_cast<const bf16x8*>(&As[16 + r][g * 8]);
    const bf16x8 bv = *reinterpret_cast<const bf16x8*>(&Bs[w * 16 + r][g * 8]);
    acc0 = __builtin_amdgcn_mfma_f32_16x16x32_bf16(av0, bv, acc0, 0, 0, 0);
    acc1 = __builtin_amdgcn_mfma_f32_16x16x32_bf16(av1, bv, acc1, 0, 0, 0);
  }

  const int col = bn + w * 16 + r;
  const float bb = bias[col];
#pragma unroll
  for (int q = 0; q < 4; ++q) {
    const int row0 = bm + g * 4 + q;
    float v0 = acc0[q] + bb;
    v0 = v0 > 0.f ? v0 : 0.f;
    Hb[(size_t)row0 * D_ + col] = f2bf(v0);
    float v1 = acc1[q] + bb;
    v1 = v1 > 0.f ? v1 : 0.f;
    Hb[(size_t)(row0 + 16) * D_ + col] = f2bf(v1);
  }
}

// ---------------------------------------------------------------------------
// GEMM2 (MFMA bf16): scores = Hb @ W2 + b2, written twice (tuple return).
// ---------------------------------------------------------------------------
__global__ __launch_bounds__(64) void gemm2_mfma(
    const unsigned short* __restrict__ Hb, const unsigned short* __restrict__ w2t,
    const float* __restrict__ b2, float* __restrict__ out) {
  const int bm = blockIdx.x * 16;
  const int bn = blockIdx.y * 16;
  const int l = threadIdx.x;
  const int r = l & 15;
  const int g = l >> 4;

  const unsigned short* ap = Hb + (size_t)(bm + r) * D_ + g * 8;
  const unsigned short* bp = w2t + (size_t)(bn + r) * D_ + g * 8;

  f32x4 acc = {0.f, 0.f, 0.f, 0.f};
#pragma unroll
  for (int k0 = 0; k0 < D_; k0 += 32) {
    const bf16x8 av = *reinterpret_cast<const bf16x8*>(ap + k0);
    const bf16x8 bv = *reinterpret_cast<const bf16x8*>(bp + k0);
    acc = __builtin_amdgcn_mfma_f32_16x16x32_bf16(av, bv, acc, 0, 0, 0);
  }

  const int col = bn + r;
  if (col < C_) {
    const float bb = b2[col];
#pragma unroll
    for (int q = 0; q < 4; ++q) {
      const int row = bm + g * 4 + q;
      const float v = acc[q] + bb;
      out[(size_t)row * C_ + col] = v;
      out[(size_t)row * C_ + col + (size_t)B_ * C_] = v;
    }
  }
}

// ---------------------------------------------------------------------------
extern "C" void kernel_launch(void* const* d_in, const int* in_sizes, int n_in,
                              void* d_out, int out_size, void* d_ws,
                              size_t ws_size, hipStream_t stream) {
  const int* ids = (const int*)d_in[0];
  const int* mask = (const int*)d_in[1];
  const float* table = (const float*)d_in[2];
  const float* W1 = (const float*)d_in[3];
  const float* b1 = (const float*)d_in[4];
  const float* W2 = (const float*)d_in[5];
  const float* b2 = (const float*)d_in[6];
  float* out = (float*)d_out;

  const size_t BOWB = (size_t)B_ * D_ * 2;          // 3.1 MB
  const size_t HBB  = (size_t)B_ * D_ * 2;          // 3.1 MB
  const size_t W1TB = (size_t)D_ * D_ * 2;          // 1.2 MB
  const size_t W2TB = (size_t)NPAD * D_ * 2;        // 172 KB
  const size_t CIDB = (size_t)B_ * S_ * 4;          // 2.1 MB

  char* p = (char*)d_ws;
  unsigned short* bowb = (unsigned short*)p;
  unsigned short* hb   = (unsigned short*)(p + BOWB);
  unsigned short* w1t  = (unsigned short*)(p + BOWB + HBB);
  unsigned short* w2t  = (unsigned short*)(p + BOWB + HBB + W1TB);
  int* cids            = (int*)(p + BOWB + HBB + W1TB + W2TB);
  int* cnts            = (int*)(p + BOWB + HBB + W1TB + W2TB + CIDB);

  compact_ids<<<B_ / 4, 256, 0, stream>>>(ids, mask, cids, cnts);
  conv_w1t<<<dim3(D_ / 32, D_ / 32), 256, 0, stream>>>(W1, w1t);
  conv_w2t<<<dim3(D_ / 32, 4), 256, 0, stream>>>(W2, w2t);
  // 3 serialized passes: one L2-resident table slice per XCD per pass
  pool_sliced<<<1024, 256, 0, stream>>>(cids, cnts, table, bowb, 0);
  pool_sliced<<<1024, 256, 0, stream>>>(cids, cnts, table, bowb, 1);
  pool_sliced<<<1024, 256, 0, stream>>>(cids, cnts, table, bowb, 2);
  gemm1_mfma<<<dim3(B_ / G1_BM, D_ / G1_BN), 256, 0, stream>>>(bowb, w1t, b1, hb);
  gemm2_mfma<<<dim3(B_ / 16, NPAD / 16), 64, 0, stream>>>(hb, w2t, b2, out);
}

// Round 8
// 95.526 us; speedup vs baseline: 1.3491x; 1.0884x over previous
//
#include <hip/hip_runtime.h>

#define B_ 2048
#define S_ 256
#define V_ 30522
#define D_ 768
#define C_ 100
#define NPAD 112  // C_ padded to 7x16 for MFMA col tiles

// ---- bf16 helpers ---------------------------------------------------------
__device__ __forceinline__ unsigned short f2bf(float x) {
  unsigned u = __builtin_bit_cast(unsigned, x);
  u = (u + 0x7fffu + ((u >> 16) & 1u)) >> 16;
  return (unsigned short)u;
}

typedef __attribute__((ext_vector_type(8))) short bf16x8;
typedef __attribute__((ext_vector_type(4))) float f32x4;

// ---------------------------------------------------------------------------
// Fused prep: [0,512) compact ids; [512,1088) W1 transpose+bf16;
// [1088,1184) W2 transpose+pad+bf16. All roles 256 threads.
// ---------------------------------------------------------------------------
__global__ __launch_bounds__(256) void prep_kernel(
    const int* __restrict__ ids, const int* __restrict__ mask,
    const float* __restrict__ w1, const float* __restrict__ w2,
    int* __restrict__ cids, int* __restrict__ cnts,
    unsigned short* __restrict__ w1t, unsigned short* __restrict__ w2t) {
  const int bid = blockIdx.x;
  if (bid < 512) {
    // ---- compact: 4 samples per block, one wave each
    const int wv = threadIdx.x >> 6, lane = threadIdx.x & 63;
    const int b = bid * 4 + wv;
    const int base = b * S_;
    int total = 0;
#pragma unroll
    for (int r = 0; r < S_ / 64; ++r) {
      const int s = r * 64 + lane;
      const int m = mask[base + s];
      const unsigned long long bal = __ballot(m != 0);
      const int pre = __popcll(bal & ((1ull << lane) - 1ull));
      if (m) cids[base + total + pre] = ids[base + s];
      total += __popcll(bal);
    }
    if (lane == 0) cnts[b] = total;
  } else if (bid < 1088) {
    // ---- W1 [768][768] f32 -> W1T [n][k] bf16
    __shared__ float tile[32][33];
    const int local = bid - 512;
    const int k0 = (local % 24) * 32, n0 = (local / 24) * 32;
    const int tx = threadIdx.x & 31, ty = threadIdx.x >> 5;
#pragma unroll
    for (int i = 0; i < 4; ++i)
      tile[ty + i * 8][tx] = w1[(size_t)(k0 + ty + i * 8) * D_ + n0 + tx];
    __syncthreads();
#pragma unroll
    for (int i = 0; i < 4; ++i) {
      const int n = ty + i * 8;
      w1t[(size_t)(n0 + n) * D_ + k0 + tx] = f2bf(tile[tx][n]);
    }
  } else {
    // ---- W2 [768][100] f32 -> W2T [112][768] bf16 (zero-padded)
    __shared__ float tile[32][33];
    const int local = bid - 1088;
    const int k0 = (local % 24) * 32, n0 = (local / 24) * 32;
    const int tx = threadIdx.x & 31, ty = threadIdx.x >> 5;
#pragma unroll
    for (int i = 0; i < 4; ++i) {
      const int k = k0 + ty + i * 8, n = n0 + tx;
      tile[ty + i * 8][tx] = (n < C_) ? w2[(size_t)k * C_ + n] : 0.f;
    }
    __syncthreads();
#pragma unroll
    for (int i = 0; i < 4; ++i) {
      const int n = n0 + ty + i * 8;
      if (n < NPAD)
        w2t[(size_t)n * D_ + k0 + tx] = f2bf(tile[tx][ty + i * 8]);
    }
  }
}

// ---------------------------------------------------------------------------
// Pool v5: XCD-pinned column-sliced gather, one pass per launch (3 passes).
// Per pass: 2048 blocks (4/CU); chunk = pass*8 + (bid&7) -> each XCD reads
// one 3.9 MB L2-resident slice. grp = bid>>3 (256 grps x 8 samples).
// Wave wv pools 2 samples; lane = 8 token-slots x 8 col-groups; inner batch
// 64 tokens = 8 outstanding float4 per lane.
// ---------------------------------------------------------------------------
__global__ __launch_bounds__(256) void pool_sliced(
    const int* __restrict__ cids, const int* __restrict__ cnts,
    const float* __restrict__ table, unsigned short* __restrict__ bowb,
    int pass) {
  __shared__ int sids[4][S_];
  const int bid = blockIdx.x;
  const int chunk = pass * 8 + (bid & 7);
  const int grp = bid >> 3;        // 0..255
  const int wv = threadIdx.x >> 6;
  const int lane = threadIdx.x & 63;
  const int sub = lane >> 3;       // token slot 0..7
  const int cg = lane & 7;         // col group (4 f32)
  const int coff = chunk * 32 + cg * 4;

  for (int i = 0; i < 2; ++i) {
    const int smp = grp * 8 + wv * 2 + i;
    const int cnt = cnts[smp];
    const int* cp = cids + (size_t)smp * S_;
    // stage ids to LDS (same-wave write->read, no barrier needed)
#pragma unroll
    for (int r = 0; r < S_ / 64; ++r) {
      const int idx = r * 64 + lane;
      sids[wv][idx] = (idx < cnt) ? cp[idx] : cp[0];
    }
    float a0 = 0.f, a1 = 0.f, a2 = 0.f, a3 = 0.f;
    for (int base = 0; base < cnt; base += 64) {
      float4 v[8];
#pragma unroll
      for (int j = 0; j < 8; ++j) {
        int t = base + j * 8 + sub;
        t = t < S_ ? t : S_ - 1;
        const int id = sids[wv][t];
        v[j] = *reinterpret_cast<const float4*>(table + (size_t)id * D_ + coff);
      }
#pragma unroll
      for (int j = 0; j < 8; ++j) {
        if (base + j * 8 + sub < cnt) {
          a0 += v[j].x; a1 += v[j].y; a2 += v[j].z; a3 += v[j].w;
        }
      }
    }
    // reduce over token slots (lane bits 3,4,5)
#pragma unroll
    for (int m = 8; m <= 32; m <<= 1) {
      a0 += __shfl_xor(a0, m);
      a1 += __shfl_xor(a1, m);
      a2 += __shfl_xor(a2, m);
      a3 += __shfl_xor(a3, m);
    }
    if (sub == 0) {
      const float inv = 1.0f / (float)cnt;
      ushort4 o;
      o.x = f2bf(a0 * inv); o.y = f2bf(a1 * inv);
      o.z = f2bf(a2 * inv); o.w = f2bf(a3 * inv);
      *reinterpret_cast<ushort4*>(bowb + (size_t)smp * D_ + coff) = o;
    }
  }
}

// ---------------------------------------------------------------------------
// GEMM1 (MFMA bf16): Hb = relu(bow @ W1 + b1), bf16 out. BM=32 BN=64 BK=64.
// 4 waves; wave w owns cols w*16..+15, 2 m-frags; 4 MFMA per k-stage.
// ---------------------------------------------------------------------------
#define G1_BM 32
#define G1_BN 64
#define G1_LDK 72  // 64 + 8 pad (ushorts) -> 144B row stride (16B aligned)

__global__ __launch_bounds__(256) void gemm1_mfma(
    const unsigned short* __restrict__ Ab, const unsigned short* __restrict__ Bt,
    const float* __restrict__ bias, unsigned short* __restrict__ Hb) {
  __shared__ unsigned short As[G1_BM][G1_LDK];
  __shared__ unsigned short Bs[G1_BN][G1_LDK];
  const int tid = threadIdx.x;
  const int bm = blockIdx.x * G1_BM;
  const int bn = blockIdx.y * G1_BN;
  const int w = tid >> 6;
  const int l = tid & 63;
  const int r = l & 15;
  const int g = l >> 4;

  f32x4 acc0 = {0.f, 0.f, 0.f, 0.f};
  f32x4 acc1 = {0.f, 0.f, 0.f, 0.f};

  const int ar = tid >> 3;          // 0..31
  const int kc8 = (tid & 7) * 8;    // 0,8,...,56
  const int br = tid >> 3;          // 0..31 (+32 for second half)

  for (int k0 = 0; k0 < D_; k0 += 64) {
    __syncthreads();
    *reinterpret_cast<int4*>(&As[ar][kc8]) =
        *reinterpret_cast<const int4*>(&Ab[(size_t)(bm + ar) * D_ + k0 + kc8]);
    *reinterpret_cast<int4*>(&Bs[br][kc8]) =
        *reinterpret_cast<const int4*>(&Bt[(size_t)(bn + br) * D_ + k0 + kc8]);
    *reinterpret_cast<int4*>(&Bs[br + 32][kc8]) =
        *reinterpret_cast<const int4*>(&Bt[(size_t)(bn + br + 32) * D_ + k0 + kc8]);
    __syncthreads();
    const bf16x8 a00 = *reinterpret_cast<const bf16x8*>(&As[r][g * 8]);
    const bf16x8 a01 = *reinterpret_cast<const bf16x8*>(&As[r][32 + g * 8]);
    const bf16x8 a10 = *reinterpret_cast<const bf16x8*>(&As[16 + r][g * 8]);
    const bf16x8 a11 = *reinterpret_cast<const bf16x8*>(&As[16 + r][32 + g * 8]);
    const bf16x8 b0 = *reinterpret_cast<const bf16x8*>(&Bs[w * 16 + r][g * 8]);
    const bf16x8 b1 = *reinterpret_cast<const bf16x8*>(&Bs[w * 16 + r][32 + g * 8]);
    acc0 = __builtin_amdgcn_mfma_f32_16x16x32_bf16(a00, b0, acc0, 0, 0, 0);
    acc0 = __builtin_amdgcn_mfma_f32_16x16x32_bf16(a01, b1, acc0, 0, 0, 0);
    acc1 = __builtin_amdgcn_mfma_f32_16x16x32_bf16(a10, b0, acc1, 0, 0, 0);
    acc1 = __builtin_amdgcn_mfma_f32_16x16x32_bf16(a11, b1, acc1, 0, 0, 0);
  }

  const int col = bn + w * 16 + r;
  const float bb = bias[col];
#pragma unroll
  for (int q = 0; q < 4; ++q) {
    const int row0 = bm + g * 4 + q;
    float v0 = acc0[q] + bb;
    v0 = v0 > 0.f ? v0 : 0.f;
    Hb[(size_t)row0 * D_ + col] = f2bf(v0);
    float v1 = acc1[q] + bb;
    v1 = v1 > 0.f ? v1 : 0.f;
    Hb[(size_t)(row0 + 16) * D_ + col] = f2bf(v1);
  }
}

// ---------------------------------------------------------------------------
// GEMM2 (MFMA bf16): scores = Hb @ W2 + b2, written twice (tuple return).
// ---------------------------------------------------------------------------
__global__ __launch_bounds__(64) void gemm2_mfma(
    const unsigned short* __restrict__ Hb, const unsigned short* __restrict__ w2t,
    const float* __restrict__ b2, float* __restrict__ out) {
  const int bm = blockIdx.x * 16;
  const int bn = blockIdx.y * 16;
  const int l = threadIdx.x;
  const int r = l & 15;
  const int g = l >> 4;

  const unsigned short* ap = Hb + (size_t)(bm + r) * D_ + g * 8;
  const unsigned short* bp = w2t + (size_t)(bn + r) * D_ + g * 8;

  f32x4 acc = {0.f, 0.f, 0.f, 0.f};
#pragma unroll
  for (int k0 = 0; k0 < D_; k0 += 32) {
    const bf16x8 av = *reinterpret_cast<const bf16x8*>(ap + k0);
    const bf16x8 bv = *reinterpret_cast<const bf16x8*>(bp + k0);
    acc = __builtin_amdgcn_mfma_f32_16x16x32_bf16(av, bv, acc, 0, 0, 0);
  }

  const int col = bn + r;
  if (col < C_) {
    const float bb = b2[col];
#pragma unroll
    for (int q = 0; q < 4; ++q) {
      const int row = bm + g * 4 + q;
      const float v = acc[q] + bb;
      out[(size_t)row * C_ + col] = v;
      out[(size_t)row * C_ + col + (size_t)B_ * C_] = v;
    }
  }
}

// ---------------------------------------------------------------------------
extern "C" void kernel_launch(void* const* d_in, const int* in_sizes, int n_in,
                              void* d_out, int out_size, void* d_ws,
                              size_t ws_size, hipStream_t stream) {
  const int* ids = (const int*)d_in[0];
  const int* mask = (const int*)d_in[1];
  const float* table = (const float*)d_in[2];
  const float* W1 = (const float*)d_in[3];
  const float* b1 = (const float*)d_in[4];
  const float* W2 = (const float*)d_in[5];
  const float* b2 = (const float*)d_in[6];
  float* out = (float*)d_out;

  const size_t BOWB = (size_t)B_ * D_ * 2;          // 3.1 MB
  const size_t HBB  = (size_t)B_ * D_ * 2;          // 3.1 MB
  const size_t W1TB = (size_t)D_ * D_ * 2;          // 1.2 MB
  const size_t W2TB = (size_t)NPAD * D_ * 2;        // 172 KB
  const size_t CIDB = (size_t)B_ * S_ * 4;          // 2.1 MB

  char* p = (char*)d_ws;
  unsigned short* bowb = (unsigned short*)p;
  unsigned short* hb   = (unsigned short*)(p + BOWB);
  unsigned short* w1t  = (unsigned short*)(p + BOWB + HBB);
  unsigned short* w2t  = (unsigned short*)(p + BOWB + HBB + W1TB);
  int* cids            = (int*)(p + BOWB + HBB + W1TB + W2TB);
  int* cnts            = (int*)(p + BOWB + HBB + W1TB + W2TB + CIDB);

  prep_kernel<<<1184, 256, 0, stream>>>(ids, mask, W1, W2, cids, cnts, w1t, w2t);
  // 3 serialized passes: one L2-resident table slice per XCD per pass
  pool_sliced<<<2048, 256, 0, stream>>>(cids, cnts, table, bowb, 0);
  pool_sliced<<<2048, 256, 0, stream>>>(cids, cnts, table, bowb, 1);
  pool_sliced<<<2048, 256, 0, stream>>>(cids, cnts, table, bowb, 2);
  gemm1_mfma<<<dim3(B_ / G1_BM, D_ / G1_BN), 256, 0, stream>>>(bowb, w1t, b1, hb);
  gemm2_mfma<<<dim3(B_ / 16, NPAD / 16), 64, 0, stream>>>(hb, w2t, b2, out);
}